// Round 6
// baseline (1570.783 us; speedup 1.0000x reference)
//
#include <hip/hip_runtime.h>

#define Nn 100000
#define Ne 100000
#define NNZC 1600000
#define NBLK 256          // virtual blocks for hist/scatter
#define CHUNK 6250        // NNZC / NBLK
#define BSH 8             // bucket = idx >> 8 (256 ids per bucket)
#define BUCKW 256
#define NBK 391           // ceil(100000/256)
#define GEMM_TOTAL 1563   // ceil(100000/64)
#define FCAP 7936         // fine-pass LDS pair cache (31 KB; buckets ~4096+-64)
#define SEGW 4            // segments per wave in gather
#define NG0 6250          // gather<0> / gather<1> virtual blocks
#define GRID 1024         // 4 blocks/CU x 256 CU, guaranteed co-resident (LDS-bound)

typedef __attribute__((ext_vector_type(8))) short short8;
typedef __attribute__((ext_vector_type(4))) float floatx4;

__device__ inline unsigned short f2bf(float f) {
    union { float f; unsigned int i; } c; c.f = f;
    unsigned int i = c.i;
    return (unsigned short)((i + 0x7fffu + ((i >> 16) & 1u)) >> 16);  // RNE
}
__device__ inline unsigned int f2bf2(float lo, float hi) {  // packed RNE
    union { float f; unsigned int i; } a, b;
    a.f = lo; b.f = hi;
    const unsigned int x = (a.i + 0x7fffu + ((a.i >> 16) & 1u)) >> 16;
    const unsigned int y = (b.i + 0x7fffu + ((b.i >> 16) & 1u)) & 0xffff0000u;
    return x | y;
}

struct FineLds {                               // 34816 B total
    int cnt[BUCKW];
    int tmp[2][BUCKW];
    unsigned int cache[FCAP];
};
union MegaLds {                                // 34816 B -> exactly 4 blocks/CU
    unsigned short wlds[128 * 136];            // gemm W staging
    struct { int a[NBK]; int b[NBK]; } s;      // hist/scatter cursors
    int scan_tmp[2][256];                      // scan1
    int red[256];                              // scan3
    FineLds f;                                 // fine pass
};

// ---- software grid barrier (persistent-kernel pattern; all GRID blocks resident) ----
// Monotonic counter: barrier k waits for counter >= k*GRID. No reset races.
__device__ inline void gsync(int* __restrict__ bar, int target, int tid) {
    __syncthreads();
    if (tid == 0) {
        __threadfence();                       // release: all prior writes visible
        atomicAdd(bar, 1);                     // device-scope by default
        while (__hip_atomic_load(bar, __ATOMIC_ACQUIRE, __HIP_MEMORY_SCOPE_AGENT) < target)
            __builtin_amdgcn_s_sleep(2);
    }
    __syncthreads();                           // broadcast acquire to the block
}

// ---- gemm block body: h[64 rows] = bf16(x @ W), operand-swapped MFMA ----
__device__ inline void gemm_block(int gb, const float* __restrict__ x,
                                  const float* __restrict__ w,
                                  unsigned short* __restrict__ h,
                                  unsigned short* wlds, int tid) {
    const int wave = tid >> 6, lane = tid & 63;
    const int q = lane >> 4, r16 = lane & 15;

    // stage W: w[k*128+n] fp32 -> wlds[n*136+k] bf16
    for (int i = tid; i < 4096; i += 256) {
        const int k = i >> 5;
        const int n0 = (i & 31) << 2;
        const float4 wv = *(const float4*)(w + k * 128 + n0);
        wlds[(n0 + 0) * 136 + k] = f2bf(wv.x);
        wlds[(n0 + 1) * 136 + k] = f2bf(wv.y);
        wlds[(n0 + 2) * 136 + k] = f2bf(wv.z);
        wlds[(n0 + 3) * 136 + k] = f2bf(wv.w);
    }
    __syncthreads();

    const int row0 = gb * 64 + wave * 16;
    const int rrow = min(row0 + r16, Nn - 1);   // clamp: x ends on a page boundary

    floatx4 acc[8];
#pragma unroll
    for (int jb = 0; jb < 8; ++jb) acc[jb] = (floatx4){0.f, 0.f, 0.f, 0.f};

    const float* ap = x + (size_t)rrow * 128 + q * 8;
#pragma unroll
    for (int kk = 0; kk < 4; ++kk) {
        const float4 a0 = *(const float4*)(ap + kk * 32);
        const float4 a1 = *(const float4*)(ap + kk * 32 + 4);
        union { unsigned int u[4]; short8 s; } xf;
        xf.u[0] = f2bf2(a0.x, a0.y);
        xf.u[1] = f2bf2(a0.z, a0.w);
        xf.u[2] = f2bf2(a1.x, a1.y);
        xf.u[3] = f2bf2(a1.z, a1.w);
        const unsigned short* wp = wlds + kk * 32 + q * 8;
#pragma unroll
        for (int jb = 0; jb < 8; ++jb) {
            const short8 wf = *(const short8*)(wp + (jb * 16 + r16) * 136);
            acc[jb] = __builtin_amdgcn_mfma_f32_16x16x32_bf16(wf, xf.s, acc[jb], 0, 0, 0);
        }
    }

    if (row0 + r16 < Nn) {
        unsigned short* hb = h + (size_t)(row0 + r16) * 128 + q * 4;
#pragma unroll
        for (int jb = 0; jb < 8; ++jb) {
            uint2 o;
            o.x = f2bf2(acc[jb][0], acc[jb][1]);
            o.y = f2bf2(acc[jb][2], acc[jb][3]);
            *(uint2*)(hb + jb * 16) = o;
        }
    }
}

// ---- hist block: coarse 391-bucket histogram partials ----
__device__ inline void hist_block(int blk, const int* __restrict__ nidx,
                                  const int* __restrict__ eidx,
                                  int* __restrict__ histN, int* __restrict__ histE,
                                  MegaLds& sm, int tid) {
    for (int j = tid; j < NBK; j += 256) { sm.s.a[j] = 0; sm.s.b[j] = 0; }
    __syncthreads();
    const int base = blk * CHUNK;
    for (int i = base + tid; i < base + CHUNK; i += 256) {
        atomicAdd(&sm.s.a[nidx[i] >> BSH], 1);
        atomicAdd(&sm.s.b[eidx[i] >> BSH], 1);
    }
    __syncthreads();
    for (int j = tid; j < NBK; j += 256) {
        histN[j * NBLK + blk] = sm.s.a[j];
        histE[j * NBLK + blk] = sm.s.b[j];
    }
}

// ---- scan1: exclusive scan within each bucket row (256 wide) ----
__device__ inline void scan1_block(int vb, int* __restrict__ histN, int* __restrict__ histE,
                                   int* __restrict__ bsumN, int* __restrict__ bsumE,
                                   MegaLds& sm, int t) {
    const int arr = vb / NBK;
    const int b = vb % NBK;
    int* a = arr ? histE : histN;
    int* bs = arr ? bsumE : bsumN;
    int v = a[b * 256 + t];
    int pin = 0;
    sm.scan_tmp[0][t] = v;
    for (int off = 1; off < 256; off <<= 1) {
        __syncthreads();
        int val = sm.scan_tmp[pin][t];
        if (t >= off) val += sm.scan_tmp[pin][t - off];
        sm.scan_tmp[1 - pin][t] = val;
        pin ^= 1;
    }
    __syncthreads();
    int incl = sm.scan_tmp[pin][t];
    a[b * 256 + t] = incl - v;      // exclusive within bucket row
    if (t == 255) bs[b] = incl;
}

// ---- scan3: add prefix of bucket totals ----
__device__ inline void scan3_block(int vb, int* __restrict__ histN, int* __restrict__ histE,
                                   const int* __restrict__ bsumN, const int* __restrict__ bsumE,
                                   MegaLds& sm, int t) {
    const int arr = vb / NBK;
    const int b = vb % NBK;
    int* a = arr ? histE : histN;
    const int* bs = arr ? bsumE : bsumN;
    int part = 0;
    for (int i = t; i < b; i += 256) part += bs[i];
    sm.red[t] = part;
    __syncthreads();
    for (int off = 128; off > 0; off >>= 1) {
        if (t < off) sm.red[t] += sm.red[t + off];
        __syncthreads();
    }
    a[b * 256 + t] += sm.red[0];
}

// ---- scatter block: bucketed pair emission ----
__device__ inline void scatter_block(int blk, const int* __restrict__ nidx,
                                     const int* __restrict__ eidx,
                                     const int* __restrict__ histN, const int* __restrict__ histE,
                                     unsigned int* __restrict__ pairsN,
                                     unsigned int* __restrict__ pairsE,
                                     MegaLds& sm, int tid) {
    for (int j = tid; j < NBK; j += 256) {
        sm.s.a[j] = histN[j * NBLK + blk];
        sm.s.b[j] = histE[j * NBLK + blk];
    }
    __syncthreads();
    const int base = blk * CHUNK;
    for (int i = base + tid; i < base + CHUNK; i += 256) {
        const int n = nidx[i], e = eidx[i];
        const int pn = atomicAdd(&sm.s.a[n >> BSH], 1);
        const int pe = atomicAdd(&sm.s.b[e >> BSH], 1);
        pairsN[pn] = ((unsigned int)e << 8) | (unsigned int)(n & 255);
        pairsE[pe] = ((unsigned int)n << 8) | (unsigned int)(e & 255);
    }
}

// ---- fine block: per-bucket local counting sort -> offs + perm ----
__device__ inline void fine_block(int b, const unsigned int* __restrict__ pairs,
                                  const int* __restrict__ hist,
                                  int* __restrict__ offs, int* __restrict__ perm,
                                  FineLds& L, int t) {
    const int S = hist[b * NBLK];
    const int E = (b + 1 < NBK) ? hist[(b + 1) * NBLK] : NNZC;
    L.cnt[t] = 0;
    __syncthreads();
    for (int i = S + t; i < E; i += BUCKW) {
        const unsigned int p = pairs[i];
        const int loc = i - S;
        if (loc < FCAP) L.cache[loc] = p;
        atomicAdd(&L.cnt[p & 255u], 1);
    }
    __syncthreads();
    int v = L.cnt[t];
    int pin = 0;
    L.tmp[0][t] = v;
    for (int off = 1; off < BUCKW; off <<= 1) {
        __syncthreads();
        int val = L.tmp[pin][t];
        if (t >= off) val += L.tmp[pin][t - off];
        L.tmp[1 - pin][t] = val;
        pin ^= 1;
    }
    __syncthreads();
    const int excl = L.tmp[pin][t] - v;
    const int id = b * BUCKW + t;
    if (id < 100000) offs[id] = S + excl;
    if (b == NBK - 1 && t == 0) offs[100000] = NNZC;
    __syncthreads();
    L.cnt[t] = excl;   // reuse as cursors
    __syncthreads();
    for (int i = S + t; i < E; i += BUCKW) {
        const int loc = i - S;
        const unsigned int p = (loc < FCAP) ? L.cache[loc] : pairs[i];
        const int pos = S + atomicAdd(&L.cnt[p & 255u], 1);
        perm[pos] = (int)(p >> 8);
    }
}

// ---- gather body: wave owns SEGW consecutive segments, 16 loads in flight ----
// MODE 0: nodes->edges (h gathered, bf16 out, scale 1/deg)
// MODE 1: edges->nodes (ef gathered, f32 out + bias, scale 1/deg)
template <int MODE>
__device__ inline void gather_body(int gblk, const int* __restrict__ perm,
                                   const int* __restrict__ offs,
                                   const void* __restrict__ srcv,
                                   const float* __restrict__ bias,
                                   void* __restrict__ outv, int tid) {
    const int wave = tid >> 6;
    const int lane = tid & 63;
    const int e0 = __builtin_amdgcn_readfirstlane((gblk * 4 + wave) * SEGW);
    const int start = offs[e0];
    const int end = offs[e0 + SEGW];
    const unsigned int laneoff = (unsigned int)lane << 2;
    const char* src = (const char*)srcv;

    float bx = 0.f, by = 0.f;
    if (MODE == 1) {
        const float2 b = ((const float2*)bias)[lane];
        bx = b.x; by = b.y;
    }

    float ax = 0.f, ay = 0.f;
    int e = e0;
    int seg_start = start;
    int nb = offs[e0 + 1];

    auto flush = [&](int deg) {
        const float sinv = deg ? 1.f / (float)deg : 0.f;
        if (MODE == 0) {
            *(unsigned int*)((char*)outv + (((unsigned int)e << 8) | laneoff)) =
                f2bf2(ax * sinv, ay * sinv);
        } else {
            float2 o;
            o.x = ax * sinv + bx;
            o.y = ay * sinv + by;
            *(float2*)((char*)outv + (((unsigned int)e << 9) | (laneoff << 1))) = o;
        }
        ax = 0.f; ay = 0.f;
        ++e;
    };

    int myv = 0;
    for (int i = start; i < end; i += 16) {
        const int t = (i - start) & 63;
        if (t == 0) myv = perm[min(i + lane, NNZC - 1)];
        const int m = min(end - i, 16);
        unsigned int a[16], u[16];
#pragma unroll
        for (int j = 0; j < 16; ++j)
            a[j] = ((unsigned int)__shfl(myv, t + (j < m ? j : m - 1), 64) << 8) | laneoff;
#pragma unroll
        for (int j = 0; j < 16; ++j) u[j] = *(const unsigned int*)(src + a[j]);
#pragma unroll
        for (int j = 0; j < 16; ++j) {
            if (j < m) {  // wave-uniform
                while (i + j == nb) {  // segment boundary (handles empty segments)
                    flush(nb - seg_start);
                    seg_start = nb;
                    nb = offs[e + 1];
                }
                ax += __uint_as_float(u[j] << 16);
                ay += __uint_as_float(u[j] & 0xffff0000u);
            }
        }
    }
    while (e < e0 + SEGW) {
        flush(end - seg_start);
        seg_start = end;
    }
}

// ---- the whole layer as one persistent kernel, phases split by software barrier ----
__global__ __launch_bounds__(256, 4) void mega_kernel(
        const int* __restrict__ nidx, const int* __restrict__ eidx,
        int* __restrict__ histN, int* __restrict__ histE,
        int* __restrict__ bsumN, int* __restrict__ bsumE,
        int* __restrict__ offsN, int* __restrict__ offsE,
        int* __restrict__ permN, int* __restrict__ permE,
        unsigned int* __restrict__ pairsN, unsigned int* __restrict__ pairsE,
        const float* __restrict__ x, const float* __restrict__ w,
        const float* __restrict__ bias,
        unsigned short* __restrict__ h, unsigned short* __restrict__ ef,
        float* __restrict__ out, int* __restrict__ bar) {
    __shared__ MegaLds sm;
    const int tid = threadIdx.x;
    const int G = gridDim.x;
    int tgt = 0;

    // P0: hist (256) + gemm [0, 768)
    for (int vb = blockIdx.x; vb < 1024; vb += G) {
        if (vb < NBLK) hist_block(vb, nidx, eidx, histN, histE, sm, tid);
        else { const int g = vb - NBLK; if (g < GEMM_TOTAL) gemm_block(g, x, w, h, sm.wlds, tid); }
        __syncthreads();
    }
    gsync(bar, tgt += G, tid);

    // P1: scan1 (782) + gemm [768, 1010)
    for (int vb = blockIdx.x; vb < 1024; vb += G) {
        if (vb < 2 * NBK) scan1_block(vb, histN, histE, bsumN, bsumE, sm, tid);
        else { const int g = 768 + vb - 2 * NBK; if (g < GEMM_TOTAL) gemm_block(g, x, w, h, sm.wlds, tid); }
        __syncthreads();
    }
    gsync(bar, tgt += G, tid);

    // P2: scan3 (782) + gemm [1010, 1252)
    for (int vb = blockIdx.x; vb < 1024; vb += G) {
        if (vb < 2 * NBK) scan3_block(vb, histN, histE, bsumN, bsumE, sm, tid);
        else { const int g = 1010 + vb - 2 * NBK; if (g < GEMM_TOTAL) gemm_block(g, x, w, h, sm.wlds, tid); }
        __syncthreads();
    }
    gsync(bar, tgt += G, tid);

    // P3: scatter (256) + gemm [1252, 1563)
    for (int vb = blockIdx.x; vb < 1024; vb += G) {
        if (vb < NBLK) scatter_block(vb, nidx, eidx, histN, histE, pairsN, pairsE, sm, tid);
        else { const int g = 1252 + vb - NBLK; if (g < GEMM_TOTAL) gemm_block(g, x, w, h, sm.wlds, tid); }
        __syncthreads();
    }
    gsync(bar, tgt += G, tid);

    // P4: fineE (391) — critical path to gather<0>
    for (int vb = blockIdx.x; vb < NBK; vb += G) {
        fine_block(vb, pairsE, histE, offsE, permE, sm.f, tid);
        __syncthreads();
    }
    gsync(bar, tgt += G, tid);

    // P5: fineN first (391, hides under fabric-bound gather), then gather<0> (6250)
    for (int vb = blockIdx.x; vb < NBK + NG0; vb += G) {
        if (vb < NBK) fine_block(vb, pairsN, histN, offsN, permN, sm.f, tid);
        else gather_body<0>(vb - NBK, permE, offsE, h, nullptr, ef, tid);
        __syncthreads();
    }
    gsync(bar, tgt += G, tid);

    // P6: gather<1> (6250) -> final output
    for (int vb = blockIdx.x; vb < NG0; vb += G) {
        gather_body<1>(vb, permN, offsN, ef, bias, out, tid);
    }
}

extern "C" void kernel_launch(void* const* d_in, const int* in_sizes, int n_in,
                              void* d_out, int out_size, void* d_ws, size_t ws_size,
                              hipStream_t stream) {
    const float* x = (const float*)d_in[0];
    const float* w = (const float*)d_in[1];
    const float* bias = (const float*)d_in[2];
    const int* hei = (const int*)d_in[3];
    const int* nidx = hei;            // row 0: node indices
    const int* eidx = hei + NNZC;     // row 1: edge indices
    float* out = (float*)d_out;

    // ---- carve workspace (256B-aligned chunks), ~79 MB ----
    char* p = (char*)d_ws;
    unsigned short* h = (unsigned short*)p;  p += (size_t)Nn * 128 * 2;      // 25.6 MB
    unsigned short* ef = (unsigned short*)p; p += (size_t)Ne * 128 * 2;      // 25.6 MB
    int* histN = (int*)p;                    p += (size_t)NBK * NBLK * 4 + 256;
    int* histE = (int*)p;                    p += (size_t)NBK * NBLK * 4 + 256;
    int* bsumN = (int*)p;                    p += 1792;
    int* bsumE = (int*)p;                    p += 1792;
    int* offsN = (int*)p;                    p += 400128;                    // 100001 ints
    int* offsE = (int*)p;                    p += 400128;
    int* permN = (int*)p;                    p += (size_t)NNZC * 4;          // 6.4 MB
    int* permE = (int*)p;                    p += (size_t)NNZC * 4;          // 6.4 MB
    unsigned int* pairsN = (unsigned int*)p; p += (size_t)NNZC * 4;          // 6.4 MB
    unsigned int* pairsE = (unsigned int*)p; p += (size_t)NNZC * 4;          // 6.4 MB
    int* bar = (int*)p;                      p += 256;                       // grid barrier

    hipMemsetAsync(bar, 0, 4, stream);   // reset barrier counter each launch

    mega_kernel<<<GRID, 256, 0, stream>>>(nidx, eidx, histN, histE, bsumN, bsumE,
                                          offsN, offsE, permN, permE, pairsN, pairsE,
                                          x, w, bias, h, ef, out, bar);
}

// Round 7
// 910.874 us; speedup vs baseline: 1.7245x; 1.7245x over previous
//
#include <hip/hip_runtime.h>

#define Nn 100000
#define Ne 100000
#define NNZC 1600000
#define NBLK 256          // virtual blocks for hist/scatter
#define CHUNK 6250        // NNZC / NBLK
#define BSH 8             // bucket = idx >> 8 (256 ids per bucket)
#define BUCKW 256
#define NBK 391           // ceil(100000/256)
#define GEMM_TOTAL 1563   // ceil(100000/64)
#define FCAP 7936         // fine-pass LDS pair cache (31 KB; buckets ~4096+-64)
#define SEGW 4            // segments per wave in gather
#define NG0 6250          // gather<0> / gather<1> virtual blocks
#define GRID 1024         // 4 blocks/CU x 256 CU, guaranteed co-resident (LDS-bound)

typedef __attribute__((ext_vector_type(8))) short short8;
typedef __attribute__((ext_vector_type(4))) float floatx4;

__device__ inline unsigned short f2bf(float f) {
    union { float f; unsigned int i; } c; c.f = f;
    unsigned int i = c.i;
    return (unsigned short)((i + 0x7fffu + ((i >> 16) & 1u)) >> 16);  // RNE
}
__device__ inline unsigned int f2bf2(float lo, float hi) {  // packed RNE
    union { float f; unsigned int i; } a, b;
    a.f = lo; b.f = hi;
    const unsigned int x = (a.i + 0x7fffu + ((a.i >> 16) & 1u)) >> 16;
    const unsigned int y = (b.i + 0x7fffu + ((b.i >> 16) & 1u)) & 0xffff0000u;
    return x | y;
}

struct FineLds {                               // 34816 B total
    int cnt[BUCKW];
    int tmp[2][BUCKW];
    unsigned int cache[FCAP];
};
union MegaLds {                                // 34816 B -> exactly 4 blocks/CU
    unsigned short wlds[128 * 136];            // gemm W staging
    struct { int a[NBK]; int b[NBK]; } s;      // hist/scatter cursors
    int scan_tmp[2][256];                      // scan1
    int red[256];                              // scan3
    FineLds f;                                 // fine pass
};

// ---- software grid barrier (persistent-kernel pattern; all GRID blocks resident) ----
// Monotonic counter: barrier k waits for counter >= k*GRID. CRITICAL: the poll is
// RELAXED (atomic loads bypass L1, observe remote adds at the coherence point,
// emit NO invalidate). Exactly ONE release fence before the add (write-back local
// L2 for cross-XCD visibility) and ONE acquire fence on exit (invalidate stale
// lines). R6's per-poll ACQUIRE load emitted buffer_inv per iteration -> a
// continuous cache-invalidate storm on every CU -> 5x uniform slowdown.
__device__ inline void gsync(int* __restrict__ bar, int target, int tid) {
    __syncthreads();
    if (tid == 0) {
        __builtin_amdgcn_fence(__ATOMIC_RELEASE, "agent");
        __hip_atomic_fetch_add(bar, 1, __ATOMIC_RELAXED, __HIP_MEMORY_SCOPE_AGENT);
        while (__hip_atomic_load(bar, __ATOMIC_RELAXED, __HIP_MEMORY_SCOPE_AGENT) < target)
            __builtin_amdgcn_s_sleep(16);
        __builtin_amdgcn_fence(__ATOMIC_ACQUIRE, "agent");
    }
    __syncthreads();                           // broadcast to the block
}

// ---- gemm block body: h[64 rows] = bf16(x @ W), operand-swapped MFMA ----
__device__ inline void gemm_block(int gb, const float* __restrict__ x,
                                  const float* __restrict__ w,
                                  unsigned short* __restrict__ h,
                                  unsigned short* wlds, int tid) {
    const int wave = tid >> 6, lane = tid & 63;
    const int q = lane >> 4, r16 = lane & 15;

    // stage W: w[k*128+n] fp32 -> wlds[n*136+k] bf16
    for (int i = tid; i < 4096; i += 256) {
        const int k = i >> 5;
        const int n0 = (i & 31) << 2;
        const float4 wv = *(const float4*)(w + k * 128 + n0);
        wlds[(n0 + 0) * 136 + k] = f2bf(wv.x);
        wlds[(n0 + 1) * 136 + k] = f2bf(wv.y);
        wlds[(n0 + 2) * 136 + k] = f2bf(wv.z);
        wlds[(n0 + 3) * 136 + k] = f2bf(wv.w);
    }
    __syncthreads();

    const int row0 = gb * 64 + wave * 16;
    const int rrow = min(row0 + r16, Nn - 1);   // clamp: x ends on a page boundary

    floatx4 acc[8];
#pragma unroll
    for (int jb = 0; jb < 8; ++jb) acc[jb] = (floatx4){0.f, 0.f, 0.f, 0.f};

    const float* ap = x + (size_t)rrow * 128 + q * 8;
#pragma unroll
    for (int kk = 0; kk < 4; ++kk) {
        const float4 a0 = *(const float4*)(ap + kk * 32);
        const float4 a1 = *(const float4*)(ap + kk * 32 + 4);
        union { unsigned int u[4]; short8 s; } xf;
        xf.u[0] = f2bf2(a0.x, a0.y);
        xf.u[1] = f2bf2(a0.z, a0.w);
        xf.u[2] = f2bf2(a1.x, a1.y);
        xf.u[3] = f2bf2(a1.z, a1.w);
        const unsigned short* wp = wlds + kk * 32 + q * 8;
#pragma unroll
        for (int jb = 0; jb < 8; ++jb) {
            const short8 wf = *(const short8*)(wp + (jb * 16 + r16) * 136);
            acc[jb] = __builtin_amdgcn_mfma_f32_16x16x32_bf16(wf, xf.s, acc[jb], 0, 0, 0);
        }
    }

    if (row0 + r16 < Nn) {
        unsigned short* hb = h + (size_t)(row0 + r16) * 128 + q * 4;
#pragma unroll
        for (int jb = 0; jb < 8; ++jb) {
            uint2 o;
            o.x = f2bf2(acc[jb][0], acc[jb][1]);
            o.y = f2bf2(acc[jb][2], acc[jb][3]);
            *(uint2*)(hb + jb * 16) = o;
        }
    }
}

// ---- hist block: coarse 391-bucket histogram partials ----
__device__ inline void hist_block(int blk, const int* __restrict__ nidx,
                                  const int* __restrict__ eidx,
                                  int* __restrict__ histN, int* __restrict__ histE,
                                  MegaLds& sm, int tid) {
    for (int j = tid; j < NBK; j += 256) { sm.s.a[j] = 0; sm.s.b[j] = 0; }
    __syncthreads();
    const int base = blk * CHUNK;
    for (int i = base + tid; i < base + CHUNK; i += 256) {
        atomicAdd(&sm.s.a[nidx[i] >> BSH], 1);
        atomicAdd(&sm.s.b[eidx[i] >> BSH], 1);
    }
    __syncthreads();
    for (int j = tid; j < NBK; j += 256) {
        histN[j * NBLK + blk] = sm.s.a[j];
        histE[j * NBLK + blk] = sm.s.b[j];
    }
}

// ---- scan1: exclusive scan within each bucket row (256 wide) ----
__device__ inline void scan1_block(int vb, int* __restrict__ histN, int* __restrict__ histE,
                                   int* __restrict__ bsumN, int* __restrict__ bsumE,
                                   MegaLds& sm, int t) {
    const int arr = vb / NBK;
    const int b = vb % NBK;
    int* a = arr ? histE : histN;
    int* bs = arr ? bsumE : bsumN;
    int v = a[b * 256 + t];
    int pin = 0;
    sm.scan_tmp[0][t] = v;
    for (int off = 1; off < 256; off <<= 1) {
        __syncthreads();
        int val = sm.scan_tmp[pin][t];
        if (t >= off) val += sm.scan_tmp[pin][t - off];
        sm.scan_tmp[1 - pin][t] = val;
        pin ^= 1;
    }
    __syncthreads();
    int incl = sm.scan_tmp[pin][t];
    a[b * 256 + t] = incl - v;      // exclusive within bucket row
    if (t == 255) bs[b] = incl;
}

// ---- scan3: add prefix of bucket totals ----
__device__ inline void scan3_block(int vb, int* __restrict__ histN, int* __restrict__ histE,
                                   const int* __restrict__ bsumN, const int* __restrict__ bsumE,
                                   MegaLds& sm, int t) {
    const int arr = vb / NBK;
    const int b = vb % NBK;
    int* a = arr ? histE : histN;
    const int* bs = arr ? bsumE : bsumN;
    int part = 0;
    for (int i = t; i < b; i += 256) part += bs[i];
    sm.red[t] = part;
    __syncthreads();
    for (int off = 128; off > 0; off >>= 1) {
        if (t < off) sm.red[t] += sm.red[t + off];
        __syncthreads();
    }
    a[b * 256 + t] += sm.red[0];
}

// ---- scatter block: bucketed pair emission ----
__device__ inline void scatter_block(int blk, const int* __restrict__ nidx,
                                     const int* __restrict__ eidx,
                                     const int* __restrict__ histN, const int* __restrict__ histE,
                                     unsigned int* __restrict__ pairsN,
                                     unsigned int* __restrict__ pairsE,
                                     MegaLds& sm, int tid) {
    for (int j = tid; j < NBK; j += 256) {
        sm.s.a[j] = histN[j * NBLK + blk];
        sm.s.b[j] = histE[j * NBLK + blk];
    }
    __syncthreads();
    const int base = blk * CHUNK;
    for (int i = base + tid; i < base + CHUNK; i += 256) {
        const int n = nidx[i], e = eidx[i];
        const int pn = atomicAdd(&sm.s.a[n >> BSH], 1);
        const int pe = atomicAdd(&sm.s.b[e >> BSH], 1);
        pairsN[pn] = ((unsigned int)e << 8) | (unsigned int)(n & 255);
        pairsE[pe] = ((unsigned int)n << 8) | (unsigned int)(e & 255);
    }
}

// ---- fine block: per-bucket local counting sort -> offs + perm ----
__device__ inline void fine_block(int b, const unsigned int* __restrict__ pairs,
                                  const int* __restrict__ hist,
                                  int* __restrict__ offs, int* __restrict__ perm,
                                  FineLds& L, int t) {
    const int S = hist[b * NBLK];
    const int E = (b + 1 < NBK) ? hist[(b + 1) * NBLK] : NNZC;
    L.cnt[t] = 0;
    __syncthreads();
    for (int i = S + t; i < E; i += BUCKW) {
        const unsigned int p = pairs[i];
        const int loc = i - S;
        if (loc < FCAP) L.cache[loc] = p;
        atomicAdd(&L.cnt[p & 255u], 1);
    }
    __syncthreads();
    int v = L.cnt[t];
    int pin = 0;
    L.tmp[0][t] = v;
    for (int off = 1; off < BUCKW; off <<= 1) {
        __syncthreads();
        int val = L.tmp[pin][t];
        if (t >= off) val += L.tmp[pin][t - off];
        L.tmp[1 - pin][t] = val;
        pin ^= 1;
    }
    __syncthreads();
    const int excl = L.tmp[pin][t] - v;
    const int id = b * BUCKW + t;
    if (id < 100000) offs[id] = S + excl;
    if (b == NBK - 1 && t == 0) offs[100000] = NNZC;
    __syncthreads();
    L.cnt[t] = excl;   // reuse as cursors
    __syncthreads();
    for (int i = S + t; i < E; i += BUCKW) {
        const int loc = i - S;
        const unsigned int p = (loc < FCAP) ? L.cache[loc] : pairs[i];
        const int pos = S + atomicAdd(&L.cnt[p & 255u], 1);
        perm[pos] = (int)(p >> 8);
    }
}

// ---- gather body: wave owns SEGW consecutive segments, 16 loads in flight ----
// MODE 0: nodes->edges (h gathered, bf16 out, scale 1/deg)
// MODE 1: edges->nodes (ef gathered, f32 out + bias, scale 1/deg)
template <int MODE>
__device__ inline void gather_body(int gblk, const int* __restrict__ perm,
                                   const int* __restrict__ offs,
                                   const void* __restrict__ srcv,
                                   const float* __restrict__ bias,
                                   void* __restrict__ outv, int tid) {
    const int wave = tid >> 6;
    const int lane = tid & 63;
    const int e0 = __builtin_amdgcn_readfirstlane((gblk * 4 + wave) * SEGW);
    const int start = offs[e0];
    const int end = offs[e0 + SEGW];
    const unsigned int laneoff = (unsigned int)lane << 2;
    const char* src = (const char*)srcv;

    float bx = 0.f, by = 0.f;
    if (MODE == 1) {
        const float2 b = ((const float2*)bias)[lane];
        bx = b.x; by = b.y;
    }

    float ax = 0.f, ay = 0.f;
    int e = e0;
    int seg_start = start;
    int nb = offs[e0 + 1];

    auto flush = [&](int deg) {
        const float sinv = deg ? 1.f / (float)deg : 0.f;
        if (MODE == 0) {
            *(unsigned int*)((char*)outv + (((unsigned int)e << 8) | laneoff)) =
                f2bf2(ax * sinv, ay * sinv);
        } else {
            float2 o;
            o.x = ax * sinv + bx;
            o.y = ay * sinv + by;
            *(float2*)((char*)outv + (((unsigned int)e << 9) | (laneoff << 1))) = o;
        }
        ax = 0.f; ay = 0.f;
        ++e;
    };

    int myv = 0;
    for (int i = start; i < end; i += 16) {
        const int t = (i - start) & 63;
        if (t == 0) myv = perm[min(i + lane, NNZC - 1)];
        const int m = min(end - i, 16);
        unsigned int a[16], u[16];
#pragma unroll
        for (int j = 0; j < 16; ++j)
            a[j] = ((unsigned int)__shfl(myv, t + (j < m ? j : m - 1), 64) << 8) | laneoff;
#pragma unroll
        for (int j = 0; j < 16; ++j) u[j] = *(const unsigned int*)(src + a[j]);
#pragma unroll
        for (int j = 0; j < 16; ++j) {
            if (j < m) {  // wave-uniform
                while (i + j == nb) {  // segment boundary (handles empty segments)
                    flush(nb - seg_start);
                    seg_start = nb;
                    nb = offs[e + 1];
                }
                ax += __uint_as_float(u[j] << 16);
                ay += __uint_as_float(u[j] & 0xffff0000u);
            }
        }
    }
    while (e < e0 + SEGW) {
        flush(end - seg_start);
        seg_start = end;
    }
}

// ---- the whole layer as one persistent kernel, phases split by software barrier ----
__global__ __launch_bounds__(256, 4) void mega_kernel(
        const int* __restrict__ nidx, const int* __restrict__ eidx,
        int* __restrict__ histN, int* __restrict__ histE,
        int* __restrict__ bsumN, int* __restrict__ bsumE,
        int* __restrict__ offsN, int* __restrict__ offsE,
        int* __restrict__ permN, int* __restrict__ permE,
        unsigned int* __restrict__ pairsN, unsigned int* __restrict__ pairsE,
        const float* __restrict__ x, const float* __restrict__ w,
        const float* __restrict__ bias,
        unsigned short* __restrict__ h, unsigned short* __restrict__ ef,
        float* __restrict__ out, int* __restrict__ bar) {
    __shared__ MegaLds sm;
    const int tid = threadIdx.x;
    const int G = gridDim.x;
    int tgt = 0;

    // P0: hist (256) + gemm [0, 768)
    for (int vb = blockIdx.x; vb < 1024; vb += G) {
        if (vb < NBLK) hist_block(vb, nidx, eidx, histN, histE, sm, tid);
        else { const int g = vb - NBLK; if (g < GEMM_TOTAL) gemm_block(g, x, w, h, sm.wlds, tid); }
        __syncthreads();
    }
    gsync(bar, tgt += G, tid);

    // P1: scan1 (782) + gemm [768, 1010)
    for (int vb = blockIdx.x; vb < 1024; vb += G) {
        if (vb < 2 * NBK) scan1_block(vb, histN, histE, bsumN, bsumE, sm, tid);
        else { const int g = 768 + vb - 2 * NBK; if (g < GEMM_TOTAL) gemm_block(g, x, w, h, sm.wlds, tid); }
        __syncthreads();
    }
    gsync(bar, tgt += G, tid);

    // P2: scan3 (782) + gemm [1010, 1252)
    for (int vb = blockIdx.x; vb < 1024; vb += G) {
        if (vb < 2 * NBK) scan3_block(vb, histN, histE, bsumN, bsumE, sm, tid);
        else { const int g = 1010 + vb - 2 * NBK; if (g < GEMM_TOTAL) gemm_block(g, x, w, h, sm.wlds, tid); }
        __syncthreads();
    }
    gsync(bar, tgt += G, tid);

    // P3: scatter (256) + gemm [1252, 1563)
    for (int vb = blockIdx.x; vb < 1024; vb += G) {
        if (vb < NBLK) scatter_block(vb, nidx, eidx, histN, histE, pairsN, pairsE, sm, tid);
        else { const int g = 1252 + vb - NBLK; if (g < GEMM_TOTAL) gemm_block(g, x, w, h, sm.wlds, tid); }
        __syncthreads();
    }
    gsync(bar, tgt += G, tid);

    // P4: fineE (391) — critical path to gather<0>
    for (int vb = blockIdx.x; vb < NBK; vb += G) {
        fine_block(vb, pairsE, histE, offsE, permE, sm.f, tid);
        __syncthreads();
    }
    gsync(bar, tgt += G, tid);

    // P5: fineN first (391, hides under fabric-bound gather), then gather<0> (6250)
    for (int vb = blockIdx.x; vb < NBK + NG0; vb += G) {
        if (vb < NBK) fine_block(vb, pairsN, histN, offsN, permN, sm.f, tid);
        else gather_body<0>(vb - NBK, permE, offsE, h, nullptr, ef, tid);
        __syncthreads();
    }
    gsync(bar, tgt += G, tid);

    // P6: gather<1> (6250) -> final output
    for (int vb = blockIdx.x; vb < NG0; vb += G) {
        gather_body<1>(vb, permN, offsN, ef, bias, out, tid);
    }
}

extern "C" void kernel_launch(void* const* d_in, const int* in_sizes, int n_in,
                              void* d_out, int out_size, void* d_ws, size_t ws_size,
                              hipStream_t stream) {
    const float* x = (const float*)d_in[0];
    const float* w = (const float*)d_in[1];
    const float* bias = (const float*)d_in[2];
    const int* hei = (const int*)d_in[3];
    const int* nidx = hei;            // row 0: node indices
    const int* eidx = hei + NNZC;     // row 1: edge indices
    float* out = (float*)d_out;

    // ---- carve workspace (256B-aligned chunks), ~79 MB ----
    char* p = (char*)d_ws;
    unsigned short* h = (unsigned short*)p;  p += (size_t)Nn * 128 * 2;      // 25.6 MB
    unsigned short* ef = (unsigned short*)p; p += (size_t)Ne * 128 * 2;      // 25.6 MB
    int* histN = (int*)p;                    p += (size_t)NBK * NBLK * 4 + 256;
    int* histE = (int*)p;                    p += (size_t)NBK * NBLK * 4 + 256;
    int* bsumN = (int*)p;                    p += 1792;
    int* bsumE = (int*)p;                    p += 1792;
    int* offsN = (int*)p;                    p += 400128;                    // 100001 ints
    int* offsE = (int*)p;                    p += 400128;
    int* permN = (int*)p;                    p += (size_t)NNZC * 4;          // 6.4 MB
    int* permE = (int*)p;                    p += (size_t)NNZC * 4;          // 6.4 MB
    unsigned int* pairsN = (unsigned int*)p; p += (size_t)NNZC * 4;          // 6.4 MB
    unsigned int* pairsE = (unsigned int*)p; p += (size_t)NNZC * 4;          // 6.4 MB
    int* bar = (int*)p;                      p += 256;                       // grid barrier

    hipMemsetAsync(bar, 0, 4, stream);   // reset barrier counter each launch

    mega_kernel<<<GRID, 256, 0, stream>>>(nidx, eidx, histN, histE, bsumN, bsumE,
                                          offsN, offsE, permN, permE, pairsN, pairsE,
                                          x, w, bias, h, ef, out, bar);
}

// Round 8
// 297.696 us; speedup vs baseline: 5.2765x; 3.0597x over previous
//
#include <hip/hip_runtime.h>

#define Nn 100000
#define Ne 100000
#define NNZC 1600000
#define NBLK 256          // blocks for scatter
#define CHUNK 6250        // NNZC / NBLK
#define BSH 8             // bucket = idx >> 8 (256 ids per bucket)
#define BUCKW 256
#define NBK 391           // ceil(100000/256)
#define CAPB 5120         // padded bucket capacity (mean 4096 + 16 sigma)
#define GEMM_TOTAL 1563   // ceil(100000/64)
#define GEMM_A 782        // gemm blocks fused with scatter
#define GEMM_B 781        // gemm blocks fused with fineE
#define FCAP 4608         // fine-pass LDS pair cache (18 KB)
#define SEGW 4            // segments per wave in gather
#define NG0 6250          // gather virtual blocks

typedef __attribute__((ext_vector_type(8))) short short8;
typedef __attribute__((ext_vector_type(4))) float floatx4;

__device__ inline unsigned short f2bf(float f) {
    union { float f; unsigned int i; } c; c.f = f;
    unsigned int i = c.i;
    return (unsigned short)((i + 0x7fffu + ((i >> 16) & 1u)) >> 16);  // RNE
}
__device__ inline unsigned int f2bf2(float lo, float hi) {  // packed RNE
    union { float f; unsigned int i; } a, b;
    a.f = lo; b.f = hi;
    const unsigned int x = (a.i + 0x7fffu + ((a.i >> 16) & 1u)) >> 16;
    const unsigned int y = (b.i + 0x7fffu + ((b.i >> 16) & 1u)) & 0xffff0000u;
    return x | y;
}

// LDS layouts
union FusedLds {                               // scatter + gemm kernel
    unsigned short wlds[128 * 136];            // 34816 B (gemm W staging)
    struct { int a[NBK]; int b[NBK]; } s;      // 3128 B (scatter counts/cursors)
};
struct FineLds {                               // fine pass (21504 B)
    int cnt[BUCKW];
    int tmp[2][BUCKW];
    unsigned int cache[FCAP];
};
union FineGemmLds {                            // fineE + gemm kernel
    unsigned short wlds[128 * 136];            // 34816 B
    FineLds f;
};

// ---- gemm block body: h[64 rows] = bf16(x @ W), operand-swapped MFMA ----
__device__ inline void gemm_block(int gb, const float* __restrict__ x,
                                  const float* __restrict__ w,
                                  unsigned short* __restrict__ h,
                                  unsigned short* wlds, int tid) {
    const int wave = tid >> 6, lane = tid & 63;
    const int q = lane >> 4, r16 = lane & 15;

    // stage W: w[k*128+n] fp32 -> wlds[n*136+k] bf16
    for (int i = tid; i < 4096; i += 256) {
        const int k = i >> 5;
        const int n0 = (i & 31) << 2;
        const float4 wv = *(const float4*)(w + k * 128 + n0);
        wlds[(n0 + 0) * 136 + k] = f2bf(wv.x);
        wlds[(n0 + 1) * 136 + k] = f2bf(wv.y);
        wlds[(n0 + 2) * 136 + k] = f2bf(wv.z);
        wlds[(n0 + 3) * 136 + k] = f2bf(wv.w);
    }
    __syncthreads();

    const int row0 = gb * 64 + wave * 16;
    const int rrow = min(row0 + r16, Nn - 1);   // clamp: x ends on a page boundary

    floatx4 acc[8];
#pragma unroll
    for (int jb = 0; jb < 8; ++jb) acc[jb] = (floatx4){0.f, 0.f, 0.f, 0.f};

    const float* ap = x + (size_t)rrow * 128 + q * 8;
#pragma unroll
    for (int kk = 0; kk < 4; ++kk) {
        const float4 a0 = *(const float4*)(ap + kk * 32);
        const float4 a1 = *(const float4*)(ap + kk * 32 + 4);
        union { unsigned int u[4]; short8 s; } xf;
        xf.u[0] = f2bf2(a0.x, a0.y);
        xf.u[1] = f2bf2(a0.z, a0.w);
        xf.u[2] = f2bf2(a1.x, a1.y);
        xf.u[3] = f2bf2(a1.z, a1.w);
        const unsigned short* wp = wlds + kk * 32 + q * 8;
#pragma unroll
        for (int jb = 0; jb < 8; ++jb) {
            const short8 wf = *(const short8*)(wp + (jb * 16 + r16) * 136);
            acc[jb] = __builtin_amdgcn_mfma_f32_16x16x32_bf16(wf, xf.s, acc[jb], 0, 0, 0);
        }
    }

    if (row0 + r16 < Nn) {
        unsigned short* hb = h + (size_t)(row0 + r16) * 128 + q * 4;
#pragma unroll
        for (int jb = 0; jb < 8; ++jb) {
            uint2 o;
            o.x = f2bf2(acc[jb][0], acc[jb][1]);
            o.y = f2bf2(acc[jb][2], acc[jb][3]);
            *(uint2*)(hb + jb * 16) = o;
        }
    }
}

// ---- fused: padded-bucket scatter (blocks [0,NBLK)) + gemm [0, GEMM_A) ----
// No hist/scan: per-block LDS counts -> one returning global atomicAdd per
// (block,bucket) reserves a contiguous range in the padded bucket region
// (memory-side atomics; R3 showed scattered STORES were the poison, not atomics).
// Pair writes stay ~16-contiguous per block per bucket (~2x line amplification).
__global__ __launch_bounds__(256) void scatter_gemm_kernel(
        const int* __restrict__ nidx, const int* __restrict__ eidx,
        int* __restrict__ gcurN, int* __restrict__ gcurE,
        unsigned int* __restrict__ pairsN, unsigned int* __restrict__ pairsE,
        const float* __restrict__ x, const float* __restrict__ w,
        unsigned short* __restrict__ h) {
    __shared__ FusedLds sm;
    const int tid = threadIdx.x;
    if (blockIdx.x < NBLK) {
        // pass 1: count
        for (int j = tid; j < NBK; j += 256) { sm.s.a[j] = 0; sm.s.b[j] = 0; }
        __syncthreads();
        const int base = blockIdx.x * CHUNK;
        for (int i = base + tid; i < base + CHUNK; i += 256) {
            atomicAdd(&sm.s.a[nidx[i] >> BSH], 1);
            atomicAdd(&sm.s.b[eidx[i] >> BSH], 1);
        }
        __syncthreads();
        // reserve: LDS slot becomes the block's bucket-local write cursor
        for (int j = tid; j < NBK; j += 256) {
            sm.s.a[j] = atomicAdd(&gcurN[j], sm.s.a[j]);
            sm.s.b[j] = atomicAdd(&gcurE[j], sm.s.b[j]);
        }
        __syncthreads();
        // pass 2: place (idx re-read is L2-hot)
        for (int i = base + tid; i < base + CHUNK; i += 256) {
            const int n = nidx[i], e = eidx[i];
            const int pn = atomicAdd(&sm.s.a[n >> BSH], 1);
            if (pn < CAPB)
                pairsN[(size_t)(n >> BSH) * CAPB + pn] =
                    ((unsigned int)e << 8) | (unsigned int)(n & 255);
            const int pe = atomicAdd(&sm.s.b[e >> BSH], 1);
            if (pe < CAPB)
                pairsE[(size_t)(e >> BSH) * CAPB + pe] =
                    ((unsigned int)n << 8) | (unsigned int)(e & 255);
        }
    } else {
        gemm_block(blockIdx.x - NBLK, x, w, h, sm.wlds, tid);
    }
}

// ---- fine block: padded bucket -> compacted CSR (offs + perm) ----
// Computes its exact compacted base S by summing bucket fills below b
// (391 L2-hot ints), then counting-sorts the bucket as before.
__device__ inline void fine_block(int b, const unsigned int* __restrict__ pairs,
                                  const int* __restrict__ gcur,
                                  int* __restrict__ offs, int* __restrict__ perm,
                                  FineLds& L, int t) {
    const int cnt_b = min(gcur[b], CAPB);
    // compacted base S = sum_{j<b} fill_j
    int part = 0;
    for (int j = t; j < b; j += 256) part += min(gcur[j], CAPB);
    L.tmp[0][t] = part;
    __syncthreads();
    for (int off = 128; off > 0; off >>= 1) {
        if (t < off) L.tmp[0][t] += L.tmp[0][t + off];
        __syncthreads();
    }
    const int S = L.tmp[0][0];
    __syncthreads();

    const unsigned int* pb = pairs + (size_t)b * CAPB;
    L.cnt[t] = 0;
    __syncthreads();
    for (int i = t; i < cnt_b; i += BUCKW) {
        const unsigned int p = pb[i];
        if (i < FCAP) L.cache[i] = p;
        atomicAdd(&L.cnt[p & 255u], 1);
    }
    __syncthreads();
    int v = L.cnt[t];
    int pin = 0;
    L.tmp[0][t] = v;
    for (int off = 1; off < BUCKW; off <<= 1) {
        __syncthreads();
        int val = L.tmp[pin][t];
        if (t >= off) val += L.tmp[pin][t - off];
        L.tmp[1 - pin][t] = val;
        pin ^= 1;
    }
    __syncthreads();
    const int excl = L.tmp[pin][t] - v;
    const int id = b * BUCKW + t;
    if (id < 100000) offs[id] = S + excl;
    if (b == NBK - 1 && t == 0) offs[100000] = NNZC;
    __syncthreads();
    L.cnt[t] = excl;   // reuse as cursors (bucket-local)
    __syncthreads();
    for (int i = t; i < cnt_b; i += BUCKW) {
        const unsigned int p = (i < FCAP) ? L.cache[i] : pb[i];
        const int pos = S + atomicAdd(&L.cnt[p & 255u], 1);
        perm[pos] = (int)(p >> 8);
    }
}

// ---- gather body: wave owns SEGW consecutive segments, flattened streaming ----
// (R1/R4 form — proven at the fabric-delivery floor, ~63 us.)
template <int MODE>
__device__ inline void gather_body(int gblk, const int* __restrict__ perm,
                                   const int* __restrict__ offs,
                                   const void* __restrict__ srcv,
                                   const float* __restrict__ bias,
                                   void* __restrict__ outv, int tid) {
    const int wave = tid >> 6;
    const int lane = tid & 63;
    const int e0 = __builtin_amdgcn_readfirstlane((gblk * 4 + wave) * SEGW);
    const int start = offs[e0];
    const int end = offs[e0 + SEGW];
    const unsigned int laneoff = (unsigned int)lane << 2;
    const char* src = (const char*)srcv;

    float bx = 0.f, by = 0.f;
    if (MODE == 1) {
        const float2 b = ((const float2*)bias)[lane];
        bx = b.x; by = b.y;
    }

    float ax = 0.f, ay = 0.f;
    int e = e0;
    int seg_start = start;
    int nb = offs[e0 + 1];

    auto flush = [&](int deg) {
        const float sinv = deg ? 1.f / (float)deg : 0.f;
        if (MODE == 0) {
            *(unsigned int*)((char*)outv + (((unsigned int)e << 8) | laneoff)) =
                f2bf2(ax * sinv, ay * sinv);
        } else {
            float2 o;
            o.x = ax * sinv + bx;
            o.y = ay * sinv + by;
            *(float2*)((char*)outv + (((unsigned int)e << 9) | (laneoff << 1))) = o;
        }
        ax = 0.f; ay = 0.f;
        ++e;
    };

    int myv = 0;
    for (int i = start; i < end; i += 8) {
        const int t = (i - start) & 63;
        if (t == 0) myv = perm[min(i + lane, NNZC - 1)];
        const int m = min(end - i, 8);
        unsigned int a[8], u[8];
#pragma unroll
        for (int j = 0; j < 8; ++j)
            a[j] = ((unsigned int)__shfl(myv, t + (j < m ? j : m - 1), 64) << 8) | laneoff;
#pragma unroll
        for (int j = 0; j < 8; ++j) u[j] = *(const unsigned int*)(src + a[j]);
#pragma unroll
        for (int j = 0; j < 8; ++j) {
            if (j < m) {  // wave-uniform
                while (i + j == nb) {  // segment boundary (handles empty segments)
                    flush(nb - seg_start);
                    seg_start = nb;
                    nb = offs[e + 1];
                }
                ax += __uint_as_float(u[j] << 16);
                ay += __uint_as_float(u[j] & 0xffff0000u);
            }
        }
    }
    while (e < e0 + SEGW) {
        flush(end - seg_start);
        seg_start = end;
    }
}

// ---- fused: fineE (blocks [0,NBK)) + gemm [GEMM_A, GEMM_TOTAL) ----
__global__ __launch_bounds__(256) void fineE_gemm_kernel(
        const unsigned int* __restrict__ pairsE, const int* __restrict__ gcurE,
        int* __restrict__ offsE, int* __restrict__ permE,
        const float* __restrict__ x, const float* __restrict__ w,
        unsigned short* __restrict__ h) {
    __shared__ FineGemmLds sm;
    const int tid = threadIdx.x;
    if (blockIdx.x < NBK) {
        fine_block(blockIdx.x, pairsE, gcurE, offsE, permE, sm.f, tid);
    } else {
        gemm_block(GEMM_A + blockIdx.x - NBK, x, w, h, sm.wlds, tid);
    }
}

// ---- fused: fineN first (blocks [0,NBK)), then gather<0> (fabric-bound) ----
__global__ __launch_bounds__(256) void g0_fineN_kernel(
        const int* __restrict__ permE, const int* __restrict__ offsE,
        const unsigned short* __restrict__ h, unsigned short* __restrict__ ef,
        const unsigned int* __restrict__ pairsN, const int* __restrict__ gcurN,
        int* __restrict__ offsN, int* __restrict__ permN) {
    __shared__ FineLds sm;
    const int tid = threadIdx.x;
    if (blockIdx.x < NBK) {
        fine_block(blockIdx.x, pairsN, gcurN, offsN, permN, sm, tid);
    } else {
        gather_body<0>(blockIdx.x - NBK, permE, offsE, h, nullptr, ef, tid);
    }
}

// ---- gather<1>: edges -> nodes, final output ----
__global__ __launch_bounds__(256) void gather_e2n_kernel(
        const int* __restrict__ permN, const int* __restrict__ offsN,
        const unsigned short* __restrict__ ef, const float* __restrict__ bias,
        float* __restrict__ out) {
    gather_body<1>(blockIdx.x, permN, offsN, ef, bias, out, threadIdx.x);
}

extern "C" void kernel_launch(void* const* d_in, const int* in_sizes, int n_in,
                              void* d_out, int out_size, void* d_ws, size_t ws_size,
                              hipStream_t stream) {
    const float* x = (const float*)d_in[0];
    const float* w = (const float*)d_in[1];
    const float* bias = (const float*)d_in[2];
    const int* hei = (const int*)d_in[3];
    const int* nidx = hei;            // row 0: node indices
    const int* eidx = hei + NNZC;     // row 1: edge indices
    float* out = (float*)d_out;

    // ---- carve workspace (256B-aligned chunks), ~81 MB ----
    char* p = (char*)d_ws;
    unsigned short* h = (unsigned short*)p;  p += (size_t)Nn * 128 * 2;      // 25.6 MB
    unsigned short* ef = (unsigned short*)p; p += (size_t)Ne * 128 * 2;      // 25.6 MB
    int* gcurN = (int*)p;                    p += NBK * 4 + 192;             // bucket fills
    int* gcurE = (int*)p;                    p += NBK * 4 + 192;
    int* offsN = (int*)p;                    p += 400128;                    // 100001 ints
    int* offsE = (int*)p;                    p += 400128;
    int* permN = (int*)p;                    p += (size_t)NNZC * 4;          // 6.4 MB
    int* permE = (int*)p;                    p += (size_t)NNZC * 4;          // 6.4 MB
    unsigned int* pairsN = (unsigned int*)p; p += (size_t)NBK * CAPB * 4;    // 8.0 MB padded
    unsigned int* pairsE = (unsigned int*)p; p += (size_t)NBK * CAPB * 4;    // 8.0 MB padded

    // zero the bucket-fill cursors (contiguous pair of arrays)
    hipMemsetAsync(gcurN, 0, 2 * (NBK * 4 + 192), stream);

    // ---- 4-launch pipeline: scatter+gemm -> fineE+gemm -> fineN+gather0 -> gather1 ----
    scatter_gemm_kernel<<<NBLK + GEMM_A, 256, 0, stream>>>(nidx, eidx, gcurN, gcurE,
                                                           pairsN, pairsE, x, w, h);
    fineE_gemm_kernel<<<NBK + GEMM_B, 256, 0, stream>>>(pairsE, gcurE, offsE, permE,
                                                        x, w, h);
    g0_fineN_kernel<<<NBK + NG0, 256, 0, stream>>>(permE, offsE, h, ef,
                                                   pairsN, gcurN, offsN, permN);
    gather_e2n_kernel<<<NG0, 256, 0, stream>>>(permN, offsN, ef, bias, out);
}